// Round 1
// baseline (130.288 us; speedup 1.0000x reference)
//
#include <hip/hip_runtime.h>
#include <hip/hip_bf16.h>

#define S_IMG    128
#define KTOP     16
#define NPTS_MAX 2048
#define RAD2     (0.02f*0.02f)
#define INV_R2   (1.0f/RAD2)
#define ZNEARF   1.0f
#define FOCALF   1.7320508075688772f   // 1/tan(30 deg)
#define ZSENT    3.0e38f

__global__ __launch_bounds__(64) void render_px(
    const float* __restrict__ points,
    const float* __restrict__ eye,
    const float* __restrict__ colors,
    float* __restrict__ out,
    int N)
{
    __shared__ float s_xy[NPTS_MAX * 2];   // packed (x_ndc, y_ndc) per point
    __shared__ float s_z[NPTS_MAX];        // view-space z, read only on hit

    const int tid  = threadIdx.x;
    const int gpix = blockIdx.x * 64 + tid;
    const int b    = gpix >> 14;            // / (128*128)
    const int p    = gpix & 16383;

    // ---- camera basis (PyTorch3D look_at: at=origin, up=+y; R cols = x,y,z) ----
    const float ex = eye[b*3+0], ey = eye[b*3+1], ez = eye[b*3+2];
    const float zinv = 1.0f / sqrtf(ex*ex + ey*ey + ez*ez);
    const float zax = -ex*zinv, zay = -ey*zinv, zaz = -ez*zinv;
    // x = normalize(cross(up, z)) = normalize((z.z, 0, -z.x))
    const float xinv = 1.0f / sqrtf(zaz*zaz + zax*zax);
    const float xax = zaz*xinv, xaz = -zax*xinv;     // xay == 0
    // y = cross(z, x)
    const float yax = zay*xaz;
    const float yay = zaz*xax - zax*xaz;
    const float yaz = -zay*xax;

    // ---- stage projected points into LDS (each thread does N/64 points) ----
    const float* pts = points + b*N*3;
    for (int j = tid; j < N; j += 64) {
        float wx = pts[3*j+0] - ex;
        float wy = pts[3*j+1] - ey;
        float wz = pts[3*j+2] - ez;
        float cz = wx*zax + wy*zay + wz*zaz;
        float xn, yn;
        if (cz > ZNEARF) {                   // visible; cz>1 implies cz>0
            float cx = wx*xax + wz*xaz;      // x-axis has zero y-component
            float cy = wx*yax + wy*yay + wz*yaz;
            float inv = FOCALF / cz;
            xn = cx*inv; yn = cy*inv;
        } else {                             // culled: park far away -> no hit
            xn = 1.0e9f; yn = 1.0e9f;
        }
        s_xy[2*j+0] = xn;
        s_xy[2*j+1] = yn;
        s_z[j] = cz;
    }
    __syncthreads();

    // ---- per-pixel scan: K nearest-in-z hits, sorted ascending ----
    const int row = p >> 7, col = p & 127;
    const float pxc = 1.0f - (2.0f*col + 1.0f) / 128.0f;   // +x left
    const float pyc = 1.0f - (2.0f*row + 1.0f) / 128.0f;   // +y up

    float    zb[KTOP];
    unsigned du[KTOP];   // (d2 bits & ~2047) | point index (N<=2048 -> 11 bits)
    #pragma unroll
    for (int q = 0; q < KTOP; ++q) { zb[q] = ZSENT; du[q] = 0u; }

    auto insert = [&](int j, float d2) {
        float nz = s_z[j];
        if (nz < zb[KTOP-1]) {
            unsigned nd = (__float_as_uint(d2) & ~2047u) | (unsigned)j;
            #pragma unroll
            for (int q = KTOP-1; q >= 1; --q) {
                bool lt  = nz < zb[q];
                bool ltp = nz < zb[q-1];
                float    zq = ltp ? zb[q-1] : nz;
                unsigned dq = ltp ? du[q-1] : nd;
                zb[q] = lt ? zq : zb[q];
                du[q] = lt ? dq : du[q];
            }
            if (nz < zb[0]) { zb[0] = nz; du[0] = nd; }
        }
    };

    const float4* s4 = reinterpret_cast<const float4*>(s_xy);
    const int n2 = N >> 1;
    for (int i = 0; i < n2; ++i) {
        float4 v = s4[i];                       // 2 points; uniform addr -> broadcast
        float dx0 = pxc - v.x, dy0 = pyc - v.y;
        float d0  = dx0*dx0 + dy0*dy0;
        float dx1 = pxc - v.z, dy1 = pyc - v.w;
        float d1  = dx1*dx1 + dy1*dy1;
        if (d0 < RAD2) insert(2*i,   d0);
        if (d1 < RAD2) insert(2*i+1, d1);
    }

    // ---- front-to-back alpha compositing ----
    const float* cols = colors + b*N*3;
    float T = 1.0f, r = 0.0f, g = 0.0f, bl = 0.0f;
    #pragma unroll
    for (int q = 0; q < KTOP; ++q) {
        if (zb[q] < 1.0e30f) {
            float d2 = __uint_as_float(du[q] & ~2047u);
            int   j  = (int)(du[q] & 2047u);
            float alpha = 1.0f - d2 * INV_R2;   // d2 < R2 -> alpha in (0,1]
            float w = alpha * T;
            r  += w * cols[3*j+0];
            g  += w * cols[3*j+1];
            bl += w * cols[3*j+2];
            T *= 1.0f - alpha;
        }
    }

    float* o = out + (size_t)gpix * 3;
    o[0] = r; o[1] = g; o[2] = bl;
}

extern "C" void kernel_launch(void* const* d_in, const int* in_sizes, int n_in,
                              void* d_out, int out_size, void* d_ws, size_t ws_size,
                              hipStream_t stream)
{
    const float* points = (const float*)d_in[0];
    const float* eye    = (const float*)d_in[1];
    const float* colors = (const float*)d_in[2];
    float* out = (float*)d_out;

    const int B = in_sizes[1] / 3;              // eye is [B,3]
    const int N = in_sizes[0] / (3 * B);        // points is [B,N,3]
    const int npix = B * S_IMG * S_IMG;

    render_px<<<npix / 64, 64, 0, stream>>>(points, eye, colors, out, N);
}

// Round 2
// 33.833 us; speedup vs baseline: 3.8509x; 3.8509x over previous
//
#include <hip/hip_runtime.h>
#include <hip/hip_bf16.h>

#define S_IMG    128
#define KTOP     16
#define NPTS_MAX 2048
#define RAD2     (0.02f*0.02f)
#define INV_R2   (1.0f/RAD2)
#define ZNEARF   1.0f
#define FOCALF   1.7320508075688772f   // 1/tan(30 deg)
#define ZSENT    3.0e38f
#define SUBS     8                     // sub-threads per pixel
#define PXB      64                    // pixels per block
#define TPB      (PXB*SUBS)            // 512 threads, 8 waves

__global__ __launch_bounds__(TPB) void render_px(
    const float* __restrict__ points,
    const float* __restrict__ eye,
    const float* __restrict__ colors,
    float* __restrict__ out,
    int N)
{
    __shared__ float s_xy[NPTS_MAX * 2];   // interleaved (x,y) -> float4 = 2 points
    __shared__ float s_z[NPTS_MAX];        // view-space z

    const int tid  = threadIdx.x;
    const int sub  = tid & (SUBS - 1);
    const int pixb = tid >> 3;                       // pixel within block
    const int gpix = blockIdx.x * PXB + pixb;
    const int b    = gpix >> 14;                     // / (128*128)
    const int p    = gpix & 16383;

    // ---- camera basis (PyTorch3D look_at: at=origin, up=+y; R cols = x,y,z) ----
    const float ex = eye[b*3+0], ey = eye[b*3+1], ez = eye[b*3+2];
    const float zinv = 1.0f / sqrtf(ex*ex + ey*ey + ez*ez);
    const float zax = -ex*zinv, zay = -ey*zinv, zaz = -ez*zinv;
    const float xinv = 1.0f / sqrtf(zaz*zaz + zax*zax);
    const float xax = zaz*xinv, xaz = -zax*xinv;     // x-axis y-component == 0
    const float yax = zay*xaz;
    const float yay = zaz*xax - zax*xaz;
    const float yaz = -zay*xax;

    // ---- stage projected points into LDS (4 points/thread) ----
    const float* pts = points + b*N*3;
    for (int j = tid; j < N; j += TPB) {
        float wx = pts[3*j+0] - ex;
        float wy = pts[3*j+1] - ey;
        float wz = pts[3*j+2] - ez;
        float cz = wx*zax + wy*zay + wz*zaz;
        float xn, yn;
        if (cz > ZNEARF) {
            float cx = wx*xax + wz*xaz;
            float cy = wx*yax + wy*yay + wz*yaz;
            float inv = FOCALF / cz;
            xn = cx*inv; yn = cy*inv;
        } else {                                     // culled: park far away
            xn = 1.0e9f; yn = 1.0e9f;
        }
        s_xy[2*j+0] = xn;
        s_xy[2*j+1] = yn;
        s_z[j] = cz;
    }
    __syncthreads();

    // ---- per-(pixel,sub) scan over N/8 points: top-16 by z, sorted ascending ----
    const int row = p >> 7, col = p & 127;
    const float pxc = 1.0f - (2.0f*col + 1.0f) / 128.0f;
    const float pyc = 1.0f - (2.0f*row + 1.0f) / 128.0f;

    float    zb[KTOP];
    unsigned du[KTOP];   // (d2 bits & ~2047) | point index (11 bits)
    #pragma unroll
    for (int q = 0; q < KTOP; ++q) { zb[q] = ZSENT; du[q] = 0u; }

    auto insert = [&](int j, float d2) {
        float nz = s_z[j];
        if (nz < zb[KTOP-1]) {
            unsigned nd = (__float_as_uint(d2) & ~2047u) | (unsigned)j;
            #pragma unroll
            for (int q = KTOP-1; q >= 1; --q) {
                bool lt  = nz < zb[q];
                bool ltp = nz < zb[q-1];
                float    zq = ltp ? zb[q-1] : nz;
                unsigned dq = ltp ? du[q-1] : nd;
                zb[q] = lt ? zq : zb[q];
                du[q] = lt ? dq : du[q];
            }
            if (nz < zb[0]) { zb[0] = nz; du[0] = nd; }
        }
    };

    const float4* s4 = reinterpret_cast<const float4*>(s_xy);
    const int nit = N / (2 * SUBS);                  // 128 float4 iters per sub
    for (int t = 0; t < nit; ++t) {
        int i = sub + SUBS * t;                      // wave: 8 uniq addrs, 32 banks
        float4 v = s4[i];
        float dx0 = pxc - v.x, dy0 = pyc - v.y;
        float d0  = dx0*dx0 + dy0*dy0;
        float dx1 = pxc - v.z, dy1 = pyc - v.w;
        float d1  = dx1*dx1 + dy1*dy1;
        if (d0 < RAD2) insert(2*i,   d0);
        if (d1 < RAD2) insert(2*i+1, d1);
    }

    // ---- merge 8 sorted lists per pixel via intra-wave shuffle, composite ----
    const float* cols = colors + b*N*3;
    const int myid = tid;                            // unique id; shfl stays in-wave
    float T = 1.0f, r = 0.0f, g = 0.0f, bl = 0.0f;

    for (int it = 0; it < KTOP; ++it) {
        // group-of-8 min over list heads (butterfly, carries payload + owner)
        float    mz  = zb[0];
        unsigned mdu = du[0];
        int      mow = myid;
        #pragma unroll
        for (int mk = 1; mk <= 4; mk <<= 1) {
            float    oz  = __shfl_xor(mz, mk, 64);
            unsigned odu = (unsigned)__shfl_xor((int)mdu, mk, 64);
            int      oow = __shfl_xor(mow, mk, 64);
            bool take = oz < mz;
            mz  = take ? oz  : mz;
            mdu = take ? odu : mdu;
            mow = take ? oow : mow;
        }
        if (__all(mz >= 1.0e30f)) break;             // every group in wave done

        if (myid == mow && mz < 1.0e30f) {           // owner pops its head
            #pragma unroll
            for (int q = 0; q < KTOP-1; ++q) { zb[q] = zb[q+1]; du[q] = du[q+1]; }
            zb[KTOP-1] = ZSENT;
        }

        if (sub == 0 && mz < 1.0e30f) {              // composite front-to-back
            float d2 = __uint_as_float(mdu & ~2047u);
            int   j  = (int)(mdu & 2047u);
            float alpha = 1.0f - d2 * INV_R2;
            float w = alpha * T;
            r  += w * cols[3*j+0];
            g  += w * cols[3*j+1];
            bl += w * cols[3*j+2];
            T *= 1.0f - alpha;
        }
    }

    if (sub == 0) {
        float* o = out + (size_t)gpix * 3;
        o[0] = r; o[1] = g; o[2] = bl;
    }
}

extern "C" void kernel_launch(void* const* d_in, const int* in_sizes, int n_in,
                              void* d_out, int out_size, void* d_ws, size_t ws_size,
                              hipStream_t stream)
{
    const float* points = (const float*)d_in[0];
    const float* eye    = (const float*)d_in[1];
    const float* colors = (const float*)d_in[2];
    float* out = (float*)d_out;

    const int B = in_sizes[1] / 3;              // eye is [B,3]
    const int N = in_sizes[0] / (3 * B);        // points is [B,N,3]
    const int npix = B * S_IMG * S_IMG;

    render_px<<<npix / PXB, TPB, 0, stream>>>(points, eye, colors, out, N);
}